// Round 3
// baseline (170.942 us; speedup 1.0000x reference)
//
#include <hip/hip_runtime.h>

#define CC 192
#define NN 16384
#define TN 64
#define XST 100   // kv Xs stride (elems): row = 50 dw -> 18*sn%32 bank starts, ~optimal
#define SST 70    // kv Ss/Vs stride: 35 dw/row
#define QXST 104  // kq Xs stride (unchanged from R2)
#define QST 200   // kq SsT stride

typedef unsigned short u16;
typedef __attribute__((ext_vector_type(4))) float f32x4;
typedef __attribute__((ext_vector_type(8))) __bf16 bf16x8;
typedef __attribute__((ext_vector_type(8))) u16 u16x8;
typedef __attribute__((ext_vector_type(4))) u16 u16x4;

union FragU { u16x8 u; bf16x8 b; };

__device__ __forceinline__ u16 f2bf(float f) {
  union { float f; unsigned u; } x; x.f = f;
  return (u16)((x.u + 0x7FFFu + ((x.u >> 16) & 1u)) >> 16);  // RNE
}
__device__ __forceinline__ float bf2f(u16 h) {
  union { unsigned u; float f; } x; x.u = ((unsigned)h) << 16;
  return x.f;
}

// lgkmcnt(0) + raw barrier: LDS handoff WITHOUT draining vmcnt (keeps global
// prefetch loads in flight across the barrier — the whole point of the pipeline).
__device__ __forceinline__ void lgkm_barrier() {
  asm volatile("s_waitcnt lgkmcnt(0)" ::: "memory");
  __builtin_amdgcn_s_barrier();
}

// ---------------- kv: pipelined K/V projections + ctx partials ----------------
// Per block: 2 token tiles x {K,V} x {hf0,hf1} = 8 phases. Phase p:
//   cvt xp[p&1] -> Xs[p&1]; issue loads for p+1; lgkm_barrier; MFMA(wp[p&1]).
// Epilogues: p==1/5 -> exp->Ss + ksum; p==3/7 -> Vs + wave-private ctx MFMA.
__global__ __launch_bounds__(256, 2)
void kv(const float* __restrict__ k, const float* __restrict__ v,
        const u16* __restrict__ Wb, const float* __restrict__ bk,
        const float* __restrict__ bv, float* __restrict__ part)
{
  __shared__ __align__(16) u16 Xs[2][TN][XST];   // 25.6 KB (doubles as Cs at end)
  __shared__ __align__(16) u16 Ss[192][SST];     // 26.9 KB
  __shared__ __align__(16) u16 Vs[192][SST];     // 26.9 KB  -> 79.4 KB total

  const int b = blockIdx.y, blk = blockIdx.x;
  const int tid = threadIdx.x;
  const int lg = (tid >> 4) & 3, lc = tid & 15;
  const int wave = tid >> 6, e0 = wave * 48;
  const int sn = tid & 63, scg = tid >> 6;

  const float* xb[2] = { k + (size_t)b * CC * NN, v + (size_t)b * CC * NN };
  const u16* Wp[2] = { Wb + 36864, Wb + 2 * 36864 };

  f32x4 acc[3][4];
  f32x4 cacc[2][2][2];
  float ksum_r[3][4];
#pragma unroll
  for (int hi = 0; hi < 2; ++hi)
#pragma unroll
    for (int mt = 0; mt < 2; ++mt)
#pragma unroll
      for (int nt = 0; nt < 2; ++nt) cacc[hi][mt][nt] = f32x4{0.f, 0.f, 0.f, 0.f};
#pragma unroll
  for (int et = 0; et < 3; ++et)
#pragma unroll
    for (int r = 0; r < 4; ++r) ksum_r[et][r] = 0.f;

  f32x4 xp[2][6];        // prefetched X (fp32), double-buffered by phase parity
  u16x8 wp[2][3][3];     // prefetched W A-frags [parity][ks][et]

  // prologue: issue phase 0 (K, hf0, tile0)
  {
    const int t0 = blk * 2 * TN;
#pragma unroll
    for (int i = 0; i < 6; ++i) {
      const float* src = xb[0] + (size_t)(scg * 4 + i * 16) * NN + t0 + sn;
      xp[0][i][0] = src[0]; xp[0][i][1] = src[NN];
      xp[0][i][2] = src[2 * NN]; xp[0][i][3] = src[3 * NN];
    }
#pragma unroll
    for (int ks = 0; ks < 3; ++ks)
#pragma unroll
      for (int et = 0; et < 3; ++et)
        wp[0][ks][et] = *reinterpret_cast<const u16x8*>(
            &Wp[0][(e0 + et * 16 + lc) * 192 + ks * 32 + lg * 8]);
  }

#pragma unroll
  for (int p = 0; p < 8; ++p) {
    const int cur = p & 1, nxt = cur ^ 1;
    const int hf = p & 1;

    // (a) convert prefetched regs -> Xs[cur]
#pragma unroll
    for (int i = 0; i < 6; ++i) {
      u16x4 pk;
      pk[0] = f2bf(xp[cur][i][0]); pk[1] = f2bf(xp[cur][i][1]);
      pk[2] = f2bf(xp[cur][i][2]); pk[3] = f2bf(xp[cur][i][3]);
      *reinterpret_cast<u16x4*>(&Xs[cur][sn][scg * 4 + i * 16]) = pk;
    }

    // (b) issue next phase's loads (stay in flight across the raw barrier)
    if (p < 7) {
      const int np = p + 1, ntile = np >> 2, nproj = (np >> 1) & 1, nhf = np & 1;
      const int nt0 = (blk * 2 + ntile) * TN;
#pragma unroll
      for (int i = 0; i < 6; ++i) {
        const float* src = xb[nproj] + (size_t)(nhf * 96 + scg * 4 + i * 16) * NN + nt0 + sn;
        xp[nxt][i][0] = src[0]; xp[nxt][i][1] = src[NN];
        xp[nxt][i][2] = src[2 * NN]; xp[nxt][i][3] = src[3 * NN];
      }
#pragma unroll
      for (int ks = 0; ks < 3; ++ks)
#pragma unroll
        for (int et = 0; et < 3; ++et)
          wp[nxt][ks][et] = *reinterpret_cast<const u16x8*>(
              &Wp[nproj][(e0 + et * 16 + lc) * 192 + nhf * 96 + ks * 32 + lg * 8]);
    }

    // (c) LDS handoff
    lgkm_barrier();

    // (d) MFMA for this phase
    if (hf == 0) {
#pragma unroll
      for (int et = 0; et < 3; ++et)
#pragma unroll
        for (int nt = 0; nt < 4; ++nt) acc[et][nt] = f32x4{0.f, 0.f, 0.f, 0.f};
    }
#pragma unroll
    for (int ks = 0; ks < 3; ++ks) {
      FragU bb[4];
#pragma unroll
      for (int nt = 0; nt < 4; ++nt)
        bb[nt].u = *reinterpret_cast<const u16x8*>(&Xs[cur][nt * 16 + lc][ks * 32 + lg * 8]);
      FragU aa;
#pragma unroll
      for (int et = 0; et < 3; ++et) {
        aa.u = wp[cur][ks][et];
#pragma unroll
        for (int nt = 0; nt < 4; ++nt)
          acc[et][nt] = __builtin_amdgcn_mfma_f32_16x16x32_bf16(aa.b, bb[nt].b,
                                                               acc[et][nt], 0, 0, 0);
      }
    }

    // (e) epilogues
    if (p == 1 || p == 5) {   // K projection complete for this tile
#pragma unroll
      for (int et = 0; et < 3; ++et)
#pragma unroll
        for (int r = 0; r < 4; ++r) {
          int e = e0 + et * 16 + lg * 4 + r;
          float bias = bk[e];
          float sum = 0.f;
#pragma unroll
          for (int nt = 0; nt < 4; ++nt) {
            float val = __expf(acc[et][nt][r] + bias);
            Ss[e][nt * 16 + lc] = f2bf(val);
            sum += val;
          }
          sum += __shfl_xor(sum, 1);
          sum += __shfl_xor(sum, 2);
          sum += __shfl_xor(sum, 4);
          sum += __shfl_xor(sum, 8);
          ksum_r[et][r] += sum;
        }
    }
    if (p == 3 || p == 7) {   // V projection complete: Vs + wave-private ctx MFMA
#pragma unroll
      for (int et = 0; et < 3; ++et)
#pragma unroll
        for (int r = 0; r < 4; ++r) {
          int e = e0 + et * 16 + lg * 4 + r;
          float bias = bv[e];
#pragma unroll
          for (int nt = 0; nt < 4; ++nt)
            Vs[e][nt * 16 + lc] = f2bf(acc[et][nt][r] + bias);
        }
      // ctx rows are wave-own (cross-wave reads only feed masked d>=24 cols)
#pragma unroll
      for (int hi = 0; hi < 2; ++hi) {
        const int base = (wave * 2 + hi) * 24;
#pragma unroll
        for (int ks2 = 0; ks2 < 2; ++ks2) {
          FragU av[2], bs[2];
#pragma unroll
          for (int mt = 0; mt < 2; ++mt) {
            int row = base + mt * 16 + lc;
            if (row > 191) row = 191;
            av[mt].u = *reinterpret_cast<const u16x8*>(&Vs[row][ks2 * 32 + lg * 8]);
            bs[mt].u = *reinterpret_cast<const u16x8*>(&Ss[row][ks2 * 32 + lg * 8]);
          }
#pragma unroll
          for (int mt = 0; mt < 2; ++mt)
#pragma unroll
            for (int nt = 0; nt < 2; ++nt)
              cacc[hi][mt][nt] = __builtin_amdgcn_mfma_f32_16x16x32_bf16(
                  av[mt].b, bs[nt].b, cacc[hi][mt][nt], 0, 0, 0);
        }
      }
    }
  }

  // ---- finale: dense, coalesced partial store via LDS bounce (reuse Xs) ----
  lgkm_barrier();                       // all waves done reading Xs
  float* Cs = (float*)&Xs[0][0][0];     // 4800 floats = 19.2 KB <= 25.6 KB
#pragma unroll
  for (int hi = 0; hi < 2; ++hi)
#pragma unroll
    for (int mt = 0; mt < 2; ++mt)
#pragma unroll
      for (int nt = 0; nt < 2; ++nt)
#pragma unroll
        for (int r = 0; r < 4; ++r) {
          int dv = mt * 16 + lg * 4 + r;
          int d = nt * 16 + lc;
          if (dv < 24 && d < 24)
            Cs[(wave * 2 + hi) * 576 + dv * 24 + d] = cacc[hi][mt][nt][r];
        }
  if (lc == 0) {
#pragma unroll
    for (int et = 0; et < 3; ++et)
#pragma unroll
      for (int r = 0; r < 4; ++r) {
        int e = e0 + et * 16 + lg * 4 + r;
        Cs[4608 + e] = ksum_r[et][r];
      }
  }
  lgkm_barrier();
  const size_t pb = (size_t)(b * 128 + blk) * 4800;
#pragma unroll
  for (int rr = 0; rr < 19; ++rr) {
    int idx = rr * 256 + tid;
    if (idx < 4800) part[pb + idx] = Cs[idx];
  }
}

// Reduce partials: ctx[b][h][d][dv] = sum_i ctxpart[dv][d] / sum_i ksumpart[d]
__global__ void kr(const float* __restrict__ part, float* __restrict__ ctx)
{
  const int id = blockIdx.x * 256 + threadIdx.x;
  if (id >= 4 * 4608) return;
  const int b = id / 4608, r = id % 4608;
  const int h = r / 576, rem = r % 576;
  const int dv = rem / 24, d = rem % 24;
  float s1 = 0.f, s2 = 0.f;
  for (int i = 0; i < 128; ++i) {
    const float* pp = part + (size_t)(b * 128 + i) * 4800;
    s1 += pp[h * 576 + dv * 24 + d];
    s2 += pp[4608 + h * 24 + d];
  }
  ctx[((b * 8 + h) * 24 + d) * 24 + dv] = s1 / s2;
}

// Meff[b][o][h*24+d] = sum_dv Wo[o][h*24+dv] * ctx[b][h][d][dv]
__global__ void km(const float* __restrict__ Wo, const float* __restrict__ ctx,
                   u16* __restrict__ Meff)
{
  const int o = blockIdx.x, b = blockIdx.y, j = threadIdx.x;
  const int h = j / 24, d = j % 24;
  const float* Wrow = Wo + o * 192 + h * 24;
  const float* crow = ctx + ((b * 8 + h) * 24 + d) * 24;
  float acc = 0.f;
#pragma unroll
  for (int dv = 0; dv < 24; ++dv) acc += Wrow[dv] * crow[dv];
  Meff[(b * 192 + o) * 192 + j] = f2bf(acc);
}

// One 192x192 (W) @ 192xTN (x fp32->bf16) GEMM for kq (unchanged structure).
__device__ __forceinline__ void gemm_stage_compute(
    const float* __restrict__ xb, const u16* __restrict__ Wp,
    int t0, int tid, f32x4 acc[3][4], u16 (*Xs)[QXST])
{
  const int lg = (tid >> 4) & 3, lc = tid & 15;
  const int wave = tid >> 6, e0 = wave * 48;
  const int sn = tid & 63, scg = tid >> 6;
#pragma unroll
  for (int et = 0; et < 3; ++et)
#pragma unroll
    for (int nt = 0; nt < 4; ++nt)
      acc[et][nt] = f32x4{0.f, 0.f, 0.f, 0.f};

#pragma unroll
  for (int hf = 0; hf < 2; ++hf) {
#pragma unroll
    for (int i = 0; i < 6; ++i) {
      int cl = scg * 4 + i * 16;
      const float* src = xb + (size_t)(hf * 96 + cl) * NN + t0 + sn;
      u16x4 p;
      p[0] = f2bf(src[0]);
      p[1] = f2bf(src[NN]);
      p[2] = f2bf(src[2 * NN]);
      p[3] = f2bf(src[3 * NN]);
      *reinterpret_cast<u16x4*>(&Xs[sn][cl]) = p;
    }
    __syncthreads();
#pragma unroll
    for (int ks = 0; ks < 3; ++ks) {
      FragU a[3], bb[4];
#pragma unroll
      for (int et = 0; et < 3; ++et)
        a[et].u = *reinterpret_cast<const u16x8*>(
            &Wp[(e0 + et * 16 + lc) * 192 + hf * 96 + ks * 32 + lg * 8]);
#pragma unroll
      for (int nt = 0; nt < 4; ++nt)
        bb[nt].u = *reinterpret_cast<const u16x8*>(&Xs[nt * 16 + lc][ks * 32 + lg * 8]);
#pragma unroll
      for (int et = 0; et < 3; ++et)
#pragma unroll
        for (int nt = 0; nt < 4; ++nt)
          acc[et][nt] = __builtin_amdgcn_mfma_f32_16x16x32_bf16(a[et].b, bb[nt].b,
                                                               acc[et][nt], 0, 0, 0);
    }
    __syncthreads();
  }
}

// Q kernel: q-proj -> SsT[n][e] -> softmax over d -> Meff GEMM -> out (+bo).
__global__ __launch_bounds__(256, 4)
void kq(const float* __restrict__ q, const u16* __restrict__ Wb,
        const float* __restrict__ bq, const u16* __restrict__ Meff,
        const float* __restrict__ bo, float* __restrict__ out)
{
  __shared__ __align__(16) u16 Xs[TN][QXST];
  __shared__ __align__(16) u16 SsT[TN][QST];

  const int b = blockIdx.y;
  const int t0 = blockIdx.x * TN;
  const int tid = threadIdx.x;
  const int lg = (tid >> 4) & 3, lc = tid & 15;
  const int wave = tid >> 6, e0 = wave * 48;
  const u16* Mb = Meff + b * 36864;

  f32x4 acc[3][4];

  gemm_stage_compute(q + (size_t)b * CC * NN, Wb, t0, tid, acc, Xs);
#pragma unroll
  for (int et = 0; et < 3; ++et)
#pragma unroll
    for (int r = 0; r < 4; ++r) {
      int e = e0 + et * 16 + lg * 4 + r;
      float bias = bq[e];
#pragma unroll
      for (int nt = 0; nt < 4; ++nt)
        SsT[nt * 16 + lc][e] = f2bf(acc[et][nt][r] + bias);
    }
  __syncthreads();

#pragma unroll
  for (int ii = 0; ii < 2; ++ii) {
    const int item = ii * 256 + tid;
    const int n = item & 63, h = item >> 6;
    u16* rowp = &SsT[n][h * 24];
    float vals[24];
    float m = -1e30f;
#pragma unroll
    for (int d = 0; d < 24; ++d) {
      vals[d] = bf2f(rowp[d]);
      m = fmaxf(m, vals[d]);
    }
    float s = 0.f;
#pragma unroll
    for (int d = 0; d < 24; ++d) { vals[d] = __expf(vals[d] - m); s += vals[d]; }
    const float inv = 1.f / s;
#pragma unroll
    for (int d = 0; d < 24; ++d) rowp[d] = f2bf(vals[d] * inv);
  }
  __syncthreads();

#pragma unroll
  for (int et = 0; et < 3; ++et)
#pragma unroll
    for (int nt = 0; nt < 4; ++nt) acc[et][nt] = f32x4{0.f, 0.f, 0.f, 0.f};
#pragma unroll
  for (int ks = 0; ks < 6; ++ks) {
    FragU a[3], bb[4];
#pragma unroll
    for (int et = 0; et < 3; ++et)
      a[et].u = *reinterpret_cast<const u16x8*>(
          &Mb[(e0 + et * 16 + lc) * 192 + ks * 32 + lg * 8]);
#pragma unroll
    for (int nt = 0; nt < 4; ++nt)
      bb[nt].u = *reinterpret_cast<const u16x8*>(&SsT[nt * 16 + lc][ks * 32 + lg * 8]);
#pragma unroll
    for (int et = 0; et < 3; ++et)
#pragma unroll
      for (int nt = 0; nt < 4; ++nt)
        acc[et][nt] = __builtin_amdgcn_mfma_f32_16x16x32_bf16(a[et].b, bb[nt].b,
                                                             acc[et][nt], 0, 0, 0);
  }

#pragma unroll
  for (int et = 0; et < 3; ++et)
#pragma unroll
    for (int r = 0; r < 4; ++r) {
      int row = e0 + et * 16 + lg * 4 + r;
      float bias = bo[row];
#pragma unroll
      for (int nt = 0; nt < 4; ++nt)
        out[(size_t)(b * 192 + row) * NN + t0 + nt * 16 + lc] = acc[et][nt][r] + bias;
    }
}

// Convert Wq/Wk/Wv to bf16 (packed [3][192][192]).
__global__ void kz(const float* __restrict__ Wq, const float* __restrict__ Wk,
                   const float* __restrict__ Wv, u16* __restrict__ Wb)
{
  const int i = blockIdx.x * 256 + threadIdx.x;
  if (i < 110592) {
    const float* src = (i < 36864) ? Wq : (i < 73728) ? Wk : Wv;
    Wb[i] = f2bf(src[i % 36864]);
  }
}

extern "C" void kernel_launch(void* const* d_in, const int* in_sizes, int n_in,
                              void* d_out, int out_size, void* d_ws, size_t ws_size,
                              hipStream_t stream)
{
  const float* q  = (const float*)d_in[0];
  const float* k  = (const float*)d_in[1];
  const float* v  = (const float*)d_in[2];
  const float* Wq = (const float*)d_in[3];
  const float* bq = (const float*)d_in[4];
  const float* Wk = (const float*)d_in[5];
  const float* bk = (const float*)d_in[6];
  const float* Wv = (const float*)d_in[7];
  const float* bv = (const float*)d_in[8];
  const float* Wo = (const float*)d_in[9];
  const float* bo = (const float*)d_in[10];
  float* out = (float*)d_out;

  // workspace carve (256B-aligned); total ~10.4 MB
  char* w = (char*)d_ws;
  u16*   Wb   = (u16*)(w);                  // 221184 B : [3][192][192] bf16
  float* part = (float*)(w + 221184);       // 9830400 B : [512][4800] (ctx 4608 + ksum 192)
  float* ctx  = (float*)(w + 10051584);     // 73728 B : [4][8][24][24]
  u16*   Meff = (u16*)(w + 10125312);       // 294912 B : [4][192][192] bf16

  hipLaunchKernelGGL(kz, dim3(432), dim3(256), 0, stream, Wq, Wk, Wv, Wb);
  hipLaunchKernelGGL(kv, dim3(128, 4), dim3(256), 0, stream, k, v, Wb, bk, bv, part);
  hipLaunchKernelGGL(kr, dim3(72), dim3(256), 0, stream, part, ctx);
  hipLaunchKernelGGL(km, dim3(192, 4), dim3(192), 0, stream, Wo, ctx, Meff);
  hipLaunchKernelGGL(kq, dim3(256, 4), dim3(256), 0, stream, q, Wb, bq, Meff, bo, out);
}